// Round 1
// baseline (232.962 us; speedup 1.0000x reference)
//
#include <hip/hip_runtime.h>
#include <math.h>

#define D 2048
#define NE 64
#define NTOK 16384
#define KSPLIT 4
#define KRANGE (D / KSPLIT)   /* 512 */
#define KSTEP 32
#define MTILE 128
#define LN_EPS 1e-5f
#define XSTRIDE (MTILE + 4)   /* 132: pad to break bank conflicts on transposed writes */

// ---------------- Kernel A: LayerNorm the expert table, store TRANSPOSED ----------------
// eT[k][e] = (emb[e][k] - mu_e) * rsqrt(var_e + eps). Transposed layout makes the
// GEMM's e-chunk staging a fully contiguous/coalesced copy.
__global__ __launch_bounds__(256) void expert_ln_kernel(
    const float* __restrict__ emb, float* __restrict__ eT) {
  const int e = blockIdx.x;
  const int tid = threadIdx.x;
  const float4* row = (const float4*)(emb + (size_t)e * D);
  float4 v0 = row[tid * 2];
  float4 v1 = row[tid * 2 + 1];
  float s = v0.x + v0.y + v0.z + v0.w + v1.x + v1.y + v1.z + v1.w;
  float q = v0.x * v0.x + v0.y * v0.y + v0.z * v0.z + v0.w * v0.w
          + v1.x * v1.x + v1.y * v1.y + v1.z * v1.z + v1.w * v1.w;
  #pragma unroll
  for (int off = 32; off > 0; off >>= 1) {
    s += __shfl_down(s, off);
    q += __shfl_down(q, off);
  }
  __shared__ float red[8];
  const int wid = tid >> 6;
  const int lane = tid & 63;
  if (lane == 0) { red[wid] = s; red[4 + wid] = q; }
  __syncthreads();
  if (tid == 0) {
    red[0] = red[0] + red[1] + red[2] + red[3];
    red[4] = red[4] + red[5] + red[6] + red[7];
  }
  __syncthreads();
  const float mu = red[0] * (1.0f / D);
  const float var = red[4] * (1.0f / D) - mu * mu;
  const float sc = rsqrtf(var + LN_EPS);
  float vals[8] = {v0.x, v0.y, v0.z, v0.w, v1.x, v1.y, v1.z, v1.w};
  const int k0 = tid * 8;
  #pragma unroll
  for (int j = 0; j < 8; ++j) {
    eT[(size_t)(k0 + j) * NE + e] = (vals[j] - mu) * sc;
  }
}

// ---------------- Kernel B: K-split partial GEMM + fused partial token stats ----------------
// Grid: (NTOK/MTILE) * KSPLIT blocks of 256 threads. Block (mt, kc) computes
// dotP[kc][mt*128 .. +128][0..64) over k in [kc*512, kc*512+512), plus partial
// sum / sumsq per token (for the token LayerNorm applied analytically at the end).
__global__ __launch_bounds__(256) void router_gemm_kernel(
    const float* __restrict__ x, const float* __restrict__ eT,
    float* __restrict__ dotP, float* __restrict__ sumP,
    float* __restrict__ sumsqP) {
  __shared__ float xT[KSTEP][XSTRIDE];
  __shared__ float eS[KSTEP][NE];
  const int tid = threadIdx.x;
  const int mt = blockIdx.x >> 2;
  const int kc = blockIdx.x & 3;
  const int K0 = kc * KRANGE;
  const int tr = tid >> 3;   // 0..31  token group (4 tokens each)
  const int tc = tid & 7;    // 0..7   expert group (8 experts each)
  const int ts = tid & 127;  // token for stats
  const int h = tid >> 7;    // which half of the k-chunk for stats

  float acc[4][8];
  #pragma unroll
  for (int i = 0; i < 4; ++i) {
    #pragma unroll
    for (int j = 0; j < 8; ++j) acc[i][j] = 0.0f;
  }
  float s1 = 0.0f, s2 = 0.0f;

  const float* xbase = x + (size_t)mt * MTILE * D + K0;

  for (int ck = 0; ck < KRANGE / KSTEP; ++ck) {
    const int kbase = ck * KSTEP;
    // stage x tile transposed: xT[k][t]
    #pragma unroll
    for (int i = 0; i < 4; ++i) {
      const int idx = tid + i * 256;        // 0..1023 over [128 tokens][8 float4]
      const int t = idx >> 3;
      const int kq = idx & 7;
      float4 v = *(const float4*)(xbase + (size_t)t * D + kbase + kq * 4);
      xT[kq * 4 + 0][t] = v.x;
      xT[kq * 4 + 1][t] = v.y;
      xT[kq * 4 + 2][t] = v.z;
      xT[kq * 4 + 3][t] = v.w;
    }
    // stage e chunk (already [k][e] in ws -> contiguous copy)
    #pragma unroll
    for (int i = 0; i < 2; ++i) {
      const int idx = tid + i * 256;        // 0..511 float4s
      *(float4*)&eS[0][idx * 4] =
          *(const float4*)(eT + (size_t)(K0 + kbase) * NE + (size_t)idx * 4);
    }
    __syncthreads();

    // fused partial stats (sum, sumsq) from the staged tile
    #pragma unroll
    for (int kk = 0; kk < 16; ++kk) {
      const float v = xT[h * 16 + kk][ts];
      s1 += v;
      s2 += v * v;
    }

    // register-tiled outer product: 4 tokens x 8 experts per thread
    #pragma unroll 8
    for (int kk = 0; kk < KSTEP; ++kk) {
      float4 xv = *(const float4*)&xT[kk][tr * 4];
      float4 ea = *(const float4*)&eS[kk][tc * 8];
      float4 eb = *(const float4*)&eS[kk][tc * 8 + 4];
      float xr[4] = {xv.x, xv.y, xv.z, xv.w};
      float er[8] = {ea.x, ea.y, ea.z, ea.w, eb.x, eb.y, eb.z, eb.w};
      #pragma unroll
      for (int i = 0; i < 4; ++i) {
        #pragma unroll
        for (int j = 0; j < 8; ++j) {
          acc[i][j] = fmaf(xr[i], er[j], acc[i][j]);
        }
      }
    }
    __syncthreads();
  }

  // combine the two half-row stats threads via LDS (xT storage reused)
  float* red = &xT[0][0];
  red[h * 128 + ts] = s1;
  red[256 + h * 128 + ts] = s2;
  __syncthreads();
  if (tid < 128) {
    const int gt = mt * MTILE + tid;
    sumP[kc * NTOK + gt] = red[tid] + red[128 + tid];
    sumsqP[kc * NTOK + gt] = red[256 + tid] + red[384 + tid];
  }

  // write dot partials: [kc][token][expert]
  float* dp = dotP + ((size_t)kc * NTOK + (size_t)mt * MTILE) * NE;
  #pragma unroll
  for (int i = 0; i < 4; ++i) {
    const int t = tr * 4 + i;
    *(float4*)&dp[(size_t)t * NE + tc * 8] =
        make_float4(acc[i][0], acc[i][1], acc[i][2], acc[i][3]);
    *(float4*)&dp[(size_t)t * NE + tc * 8 + 4] =
        make_float4(acc[i][4], acc[i][5], acc[i][6], acc[i][7]);
  }
}

// ---------------- Kernel C: reduce partials, top-2, softmax gates ----------------
__global__ __launch_bounds__(256) void finalize_kernel(
    const float* __restrict__ dotP, const float* __restrict__ sumP,
    const float* __restrict__ sumsqP, float* __restrict__ out) {
  const int t = blockIdx.x * 256 + threadIdx.x;
  float s1 = 0.0f, s2 = 0.0f;
  #pragma unroll
  for (int kc = 0; kc < KSPLIT; ++kc) {
    s1 += sumP[kc * NTOK + t];
    s2 += sumsqP[kc * NTOK + t];
  }
  const float mu = s1 * (1.0f / D);
  const float var = s2 * (1.0f / D) - mu * mu;
  const float sc = rsqrtf(var + LN_EPS);  // sim = dot * sc  (sum(e_norm)==0)

  float d[NE];
  #pragma unroll
  for (int e = 0; e < NE; ++e) d[e] = 0.0f;
  #pragma unroll
  for (int kc = 0; kc < KSPLIT; ++kc) {
    const float* dp = dotP + ((size_t)kc * NTOK + t) * NE;
    #pragma unroll
    for (int eq = 0; eq < NE / 4; ++eq) {
      float4 v = *(const float4*)&dp[eq * 4];
      d[eq * 4 + 0] += v.x;
      d[eq * 4 + 1] += v.y;
      d[eq * 4 + 2] += v.z;
      d[eq * 4 + 3] += v.w;
    }
  }

  float w1 = -INFINITY, w2 = -INFINITY;
  int i1 = 0, i2 = 0;
  #pragma unroll
  for (int e = 0; e < NE; ++e) {
    const float v = d[e] * sc;
    if (v > w1) {
      w2 = w1; i2 = i1; w1 = v; i1 = e;
    } else if (v > w2) {
      w2 = v; i2 = e;
    }
  }
  const float invT = 0.02209708691207961f;  // 1/sqrt(2048)
  const float e1 = expf((w2 - w1) * invT);
  const float g1 = 1.0f / (1.0f + e1);
  const float g2 = e1 / (1.0f + e1);

  // outputs: [indices as float][gates], each [NTOK][2] flat
  out[t * 2 + 0] = (float)i1;
  out[t * 2 + 1] = (float)i2;
  out[2 * NTOK + t * 2 + 0] = g1;
  out[2 * NTOK + t * 2 + 1] = g2;
}

extern "C" void kernel_launch(void* const* d_in, const int* in_sizes, int n_in,
                              void* d_out, int out_size, void* d_ws, size_t ws_size,
                              hipStream_t stream) {
  const float* x = (const float*)d_in[0];     // [4,4096,2048] f32
  const float* emb = (const float*)d_in[1];   // [64,2048] f32
  float* ws = (float*)d_ws;
  float* eT = ws;                              // 2048*64            = 131072 floats
  float* dotP = ws + 131072;                   // 4*16384*64         = 4194304 floats
  float* sumP = dotP + (size_t)KSPLIT * NTOK * NE;   // 4*16384 floats
  float* sumsqP = sumP + (size_t)KSPLIT * NTOK;      // 4*16384 floats
  float* out = (float*)d_out;

  expert_ln_kernel<<<NE, 256, 0, stream>>>(emb, eT);
  router_gemm_kernel<<<(NTOK / MTILE) * KSPLIT, 256, 0, stream>>>(
      x, eT, dotP, sumP, sumsqP);
  finalize_kernel<<<NTOK / 256, 256, 0, stream>>>(dotP, sumP, sumsqP, out);
}